// Round 6
// baseline (436.484 us; speedup 1.0000x reference)
//
#include <hip/hip_runtime.h>
#include <math.h>

#ifndef M_PI
#define M_PI 3.14159265358979323846
#endif

typedef _Float16 half_t;

constexpr int S_LEN    = 176400;
constexpr int NFFT     = 2048;
constexpr int NC       = 1024;
constexpr int HOP_     = 441;
constexpr int T_FRAMES = 401;
constexpr int F_BINS   = 1025;
constexpr int F_STRIDE_H = 1032;   // halves per spec row (8-aligned)
constexpr int N_CH     = 64;
constexpr float EPS_   = 1e-8f;
constexpr float C1_    = 0.0004f;
constexpr float C2_    = 0.0036f;
constexpr float COV_NORM_ = 49.0f / 48.0f;

// workspace float offsets (tables), spec area (fp16) starts at SPEC_OFF floats
constexpr int WINP_OFF = 0;        // float2[1024]  window pairs
constexpr int TG1_OFF  = 2048;     // float2[16*64] w1024^(L*k1) [k1][L]
constexpr int TG2_OFF  = 4096;     // float2[16*4]  w64^(n3*k2)  [k2][n3]
constexpr int UTW_OFF  = 4224;     // float2[1025]
constexpr int SPEC_OFF = 6400;
constexpr int RPB_     = 10;
constexpr int N_CHUNKS = 40;

#define WAVE_SYNC() asm volatile("s_waitcnt lgkmcnt(0)" ::: "memory")

__device__ __forceinline__ float2 cadd(float2 a, float2 b){ return make_float2(a.x+b.x, a.y+b.y); }
__device__ __forceinline__ float2 csub(float2 a, float2 b){ return make_float2(a.x-b.x, a.y-b.y); }
__device__ __forceinline__ float2 cmul(float2 a, float2 b){ return make_float2(a.x*b.x-a.y*b.y, a.x*b.y+a.y*b.x); }
__device__ __forceinline__ float2 mulnegi(float2 v){ return make_float2(v.y, -v.x); }  // -i*v

__device__ __constant__ float2 W16C[10] = {
    { 1.0f, 0.0f},
    { 0.92387953251128674f, -0.38268343236508978f},
    { 0.70710678118654752f, -0.70710678118654752f},
    { 0.38268343236508978f, -0.92387953251128674f},
    { 0.0f, -1.0f},
    {-0.38268343236508978f, -0.92387953251128674f},
    {-0.70710678118654752f, -0.70710678118654752f},
    {-0.92387953251128674f, -0.38268343236508978f},
    {-1.0f, 0.0f},
    {-0.92387953251128674f,  0.38268343236508978f},
};

// 16-pt DFT in registers (natural order in/out)
__device__ __forceinline__ void fft16(float2 (&r)[16]) {
    float2 C[4][4];
    #pragma unroll
    for (int m2 = 0; m2 < 4; ++m2) {
        float2 u0 = r[m2], u1 = r[4+m2], u2 = r[8+m2], u3 = r[12+m2];
        float2 t0 = cadd(u0,u2), t1 = csub(u0,u2), t2 = cadd(u1,u3), t3 = csub(u1,u3);
        C[0][m2] = cadd(t0,t2);
        C[1][m2] = cadd(t1, mulnegi(t3));
        C[2][m2] = csub(t0,t2);
        C[3][m2] = csub(t1, mulnegi(t3));
    }
    #pragma unroll
    for (int a = 0; a < 4; ++a) {
        float2 u0 = C[a][0];
        float2 u1 = (a == 0) ? C[a][1] : cmul(C[a][1], W16C[a]);
        float2 u2 = (a == 0) ? C[a][2] : cmul(C[a][2], W16C[2*a]);
        float2 u3 = (a == 0) ? C[a][3] : cmul(C[a][3], W16C[3*a]);
        float2 t0 = cadd(u0,u2), t1 = csub(u0,u2), t2 = cadd(u1,u3), t3 = csub(u1,u3);
        r[a]      = cadd(t0,t2);
        r[a+4]    = cadd(t1, mulnegi(t3));
        r[a+8]    = csub(t0,t2);
        r[a+12]   = csub(t1, mulnegi(t3));
    }
}

__global__ __launch_bounds__(256) void init_tables_kernel(float* __restrict__ ws, float* __restrict__ out) {
    const int idx = blockIdx.x * 256 + threadIdx.x;
    if (idx < 64) out[idx] = 0.0f;
    if (idx < 1024) {
        float w0 = 0.5f - 0.5f * cosf((float)(2.0 * M_PI / NFFT) * (float)(2*idx));
        float w1 = 0.5f - 0.5f * cosf((float)(2.0 * M_PI / NFFT) * (float)(2*idx+1));
        ws[WINP_OFF + 2*idx]   = w0;
        ws[WINP_OFF + 2*idx+1] = w1;
    }
    if (idx < 1024) {
        int k1 = idx >> 6, L = idx & 63;
        float ang = -2.0f * (float)M_PI * (float)(L * k1) / (float)NC;
        float s, c; sincosf(ang, &s, &c);
        ws[TG1_OFF + 2*idx] = c; ws[TG1_OFF + 2*idx+1] = s;
    }
    if (idx < 64) {
        int k2 = idx >> 2, n3 = idx & 3;
        float ang = -2.0f * (float)M_PI * (float)(n3 * k2) / 64.0f;
        float s, c; sincosf(ang, &s, &c);
        ws[TG2_OFF + 2*idx] = c; ws[TG2_OFF + 2*idx+1] = s;
    }
    if (idx < F_BINS) {
        float ang = -(float)M_PI * (float)idx / (float)NC;
        float s, c; sincosf(ang, &s, &c);
        ws[UTW_OFF + 2*idx] = c; ws[UTW_OFF + 2*idx+1] = s;
    }
}

// One WAVE per 1024-pt FFT; 2 waves/block (t, t+1 of same channel+input).
// LDS: 4.3 KB/wave via split re/im transpose passes through one float buffer.
// Layouts: T_A addr=17*Lsrc+k1 ; T_B addr=68*k2+Lsrc ; stage3->unpack natural.
__global__ __launch_bounds__(128, 6) void stft_mag_kernel(
    const float* __restrict__ x0, const float* __restrict__ x1,
    float* __restrict__ ws, int ch0, int nch, int swizzle)
{
    __shared__ float ldsf[2][1088];

    const int tid  = threadIdx.x;
    const int wave = tid >> 6;
    const int L    = tid & 63;

    int ch, pair, which;
    if (swizzle) {
        int g = blockIdx.x;
        ch    = ch0 + (g & 7) * 8 + ((g >> 3) & 7);
        which = (g >> 6) & 1;
        pair  = g >> 7;
    } else {
        int bx = blockIdx.x;
        which = bx / 201;
        pair  = bx - which * 201;
        ch    = ch0 + blockIdx.y;
    }
    const int t = 2 * pair + wave;
    if (t > 400) return;                 // no barriers in kernel; safe

    const float* __restrict__ xin = (which ? x1 : x0) + (size_t)ch * S_LEN;
    const float2* __restrict__ winp = (const float2*)(ws + WINP_OFF);
    const float2* __restrict__ tg1  = (const float2*)(ws + TG1_OFF);
    const float2* __restrict__ tg2  = (const float2*)(ws + TG2_OFF);
    const float2* __restrict__ utw  = (const float2*)(ws + UTW_OFF);
    float* B = ldsf[wave];

    // ---- load comb + window: r[n1] = (x[2c]w[2c], x[2c+1]w[2c+1]), c = 64*n1 + L
    float2 r[16];
    const int base = t * HOP_ - 1024;
    #pragma unroll
    for (int j = 0; j < 16; ++j) {
        const int s0 = base + 128 * j;
        const int i0 = s0 + 2 * L;
        float2 wp = winp[(j << 6) + L];
        float a, b;
        if (s0 >= 0 && s0 + 128 <= S_LEN) {
            a = xin[i0]; b = xin[i0 + 1];
        } else {
            int ia = i0;     ia = (ia < 0) ? -ia : ia; ia = (ia >= S_LEN) ? 2*S_LEN-2-ia : ia;
            int ib = i0 + 1; ib = (ib < 0) ? -ib : ib; ib = (ib >= S_LEN) ? 2*S_LEN-2-ib : ib;
            a = xin[ia]; b = xin[ib];
        }
        r[j] = make_float2(a * wp.x, b * wp.y);
    }

    // ---- stage 1: fft16 over n1 + twiddle w1024^{L*k1}
    fft16(r);
    #pragma unroll
    for (int k1 = 1; k1 < 16; ++k1) r[k1] = cmul(r[k1], tg1[(k1 << 6) + L]);

    // ---- transpose A (split re/im): write addr 17*L + k1, read 68*n2 + 17*n3 + k1
    const int k1t = L & 15, n3t = L >> 4;
    const int offA = 17 * n3t + k1t;
    float sre[16], sim_[16];
    {
        const int wbase = 17 * L;
        #pragma unroll
        for (int k1 = 0; k1 < 16; ++k1) B[wbase + k1] = r[k1].x;
        WAVE_SYNC();
        #pragma unroll
        for (int n2 = 0; n2 < 16; ++n2) sre[n2] = B[68 * n2 + offA];
        WAVE_SYNC();
        #pragma unroll
        for (int k1 = 0; k1 < 16; ++k1) B[wbase + k1] = r[k1].y;
        WAVE_SYNC();
        #pragma unroll
        for (int n2 = 0; n2 < 16; ++n2) sim_[n2] = B[68 * n2 + offA];
        WAVE_SYNC();
    }

    // ---- stage 2: fft16 over n2 + twiddle w64^{n3*k2}
    float2 s[16];
    #pragma unroll
    for (int n2 = 0; n2 < 16; ++n2) s[n2] = make_float2(sre[n2], sim_[n2]);
    fft16(s);
    #pragma unroll
    for (int k2 = 1; k2 < 16; ++k2) s[k2] = cmul(s[k2], tg2[(k2 << 2) + n3t]);

    // ---- transpose B (split re/im): write addr 68*k2 + L, read 272*g4 + k1b + 68*rr + 16*n3
    const int g4 = L >> 4, k1b = L & 15;
    const int base3 = 272 * g4 + k1b;
    float dre[16], dim_[16];
    {
        #pragma unroll
        for (int k2 = 0; k2 < 16; ++k2) B[68 * k2 + L] = s[k2].x;
        WAVE_SYNC();
        #pragma unroll
        for (int rr = 0; rr < 4; ++rr)
            #pragma unroll
            for (int n3 = 0; n3 < 4; ++n3) dre[4*rr+n3] = B[base3 + 68*rr + 16*n3];
        WAVE_SYNC();
        #pragma unroll
        for (int k2 = 0; k2 < 16; ++k2) B[68 * k2 + L] = s[k2].y;
        WAVE_SYNC();
        #pragma unroll
        for (int rr = 0; rr < 4; ++rr)
            #pragma unroll
            for (int n3 = 0; n3 < 4; ++n3) dim_[4*rr+n3] = B[base3 + 68*rr + 16*n3];
        WAVE_SYNC();
    }

    // ---- stage 3: 4-pt DFT over n3 (w4 = -i); outputs o[rr*4+k3] at k = kb + 256*k3
    float2 o[16];
    #pragma unroll
    for (int rr = 0; rr < 4; ++rr) {
        float2 D0 = make_float2(dre[4*rr+0], dim_[4*rr+0]);
        float2 D1 = make_float2(dre[4*rr+1], dim_[4*rr+1]);
        float2 D2 = make_float2(dre[4*rr+2], dim_[4*rr+2]);
        float2 D3 = make_float2(dre[4*rr+3], dim_[4*rr+3]);
        float2 e0 = cadd(D0, D2), e1 = csub(D0, D2);
        float2 e2 = cadd(D1, D3), e3 = csub(D1, D3);
        o[4*rr+0] = cadd(e0, e2);
        o[4*rr+1] = cadd(e1, mulnegi(e3));
        o[4*rr+2] = csub(e0, e2);
        o[4*rr+3] = csub(e1, mulnegi(e3));
    }

    // ---- stage3 -> unpack (split re/im), natural layout k = k1b + 16*rr + 64*g4 + 256*k3
    const int kb0 = k1b + (g4 << 6);
    float zr_re[8], zn_re[8], zr_im[8], zn_im[8];
    float z5x, z5y;
    {
        #pragma unroll
        for (int rr = 0; rr < 4; ++rr)
            #pragma unroll
            for (int k3 = 0; k3 < 4; ++k3) B[kb0 + (rr << 4) + (k3 << 8)] = o[4*rr+k3].x;
        WAVE_SYNC();
        #pragma unroll
        for (int j = 0; j < 8; ++j) {
            zr_re[j] = B[(j << 6) + L];
            zn_re[j] = B[(1024 - (j << 6) - L) & 1023];
        }
        z5x = B[512];
        WAVE_SYNC();
        #pragma unroll
        for (int rr = 0; rr < 4; ++rr)
            #pragma unroll
            for (int k3 = 0; k3 < 4; ++k3) B[kb0 + (rr << 4) + (k3 << 8)] = o[4*rr+k3].y;
        WAVE_SYNC();
        #pragma unroll
        for (int j = 0; j < 8; ++j) {
            zr_im[j] = B[(j << 6) + L];
            zn_im[j] = B[(1024 - (j << 6) - L) & 1023];
        }
        z5y = B[512];
    }

    // ---- real-FFT unpack: bins m = 64j+L and 1024-m share (E,O,w) up to signs
    half_t* __restrict__ sout =
        (half_t*)(ws + SPEC_OFF)
        + ((size_t)which * nch + (size_t)(ch - ch0)) * (size_t)T_FRAMES * F_STRIDE_H
        + (size_t)t * F_STRIDE_H;
    #pragma unroll
    for (int j = 0; j < 8; ++j) {
        const int m = (j << 6) + L;
        float Ex = 0.5f * (zr_re[j] + zn_re[j]);
        float Ey = 0.5f * (zr_im[j] - zn_im[j]);
        float Ox = 0.5f * (zr_im[j] + zn_im[j]);
        float Oy = 0.5f * (zn_re[j] - zr_re[j]);
        float2 wu = utw[m];
        float Xx = Ex + wu.x * Ox - wu.y * Oy;
        float Xy = Ey + wu.x * Oy + wu.y * Ox;
        sout[m] = (half_t)sqrtf(fmaxf(Xx * Xx + Xy * Xy, EPS_));
        float Xx2 = Ex - wu.x * Ox + wu.y * Oy;
        float Xy2 = -Ey + wu.x * Oy + wu.y * Ox;
        sout[1024 - m] = (half_t)sqrtf(fmaxf(Xx2 * Xx2 + Xy2 * Xy2, EPS_));
    }
    if (L == 0) {
        sout[512] = (half_t)sqrtf(fmaxf(z5x * z5x + z5y * z5y, EPS_));
    }
}

__device__ __forceinline__ float4 load4h(const half_t* __restrict__ p) {
    uint2 u = *(const uint2*)p;
    union { unsigned v; half_t h[2]; } a, b;
    a.v = u.x; b.v = u.y;
    return make_float4((float)a.h[0], (float)a.h[1], (float)b.h[0], (float)b.h[1]);
}

// SSIM: thread owns 4 consecutive cols; fp16 spec loads; rolling vertical sums;
// 5 scalar LDS arrays, lane stride 5 words -> conflict-free.
__global__ __launch_bounds__(256) void ssim_kernel(
    const float* __restrict__ ws, float* __restrict__ out,
    int ch0, int nch)
{
    __shared__ float csx[1284], csy[1284], csxx[1284], csyy[1284], csxy[1284];
    __shared__ double red[256];

    const int tid = threadIdx.x;
    const int cg  = blockIdx.y;
    const int ch  = ch0 + cg;
    const half_t* __restrict__ spec = (const half_t*)(ws + SPEC_OFF);
    const size_t per_ch = (size_t)T_FRAMES * F_STRIDE_H;
    const half_t* __restrict__ X = spec + (size_t)cg * per_ch;
    const half_t* __restrict__ Y = spec + ((size_t)nch + cg) * per_ch;

    const int t_begin = 3 + blockIdx.x * RPB_;
    const int t_end_  = min(t_begin + RPB_, T_FRAMES - 3);

    const int fv = tid << 2;
    const bool last = (tid == 255);
    const float inv49 = 1.0f / 49.0f;
    double acc = 0.0;

    float sx[4] = {0,0,0,0}, sy[4] = {0,0,0,0}, sxx[4] = {0,0,0,0},
          syy[4] = {0,0,0,0}, sxy[4] = {0,0,0,0};
    float s5[5] = {0,0,0,0,0};

    for (int rr = t_begin - 3; rr < t_begin + 3; ++rr) {
        float4 xv = load4h(X + (size_t)rr * F_STRIDE_H + fv);
        float4 yv = load4h(Y + (size_t)rr * F_STRIDE_H + fv);
        float xa[4] = {xv.x, xv.y, xv.z, xv.w}, ya[4] = {yv.x, yv.y, yv.z, yv.w};
        #pragma unroll
        for (int c = 0; c < 4; ++c) {
            sx[c] += xa[c]; sy[c] += ya[c];
            sxx[c] += xa[c]*xa[c]; syy[c] += ya[c]*ya[c]; sxy[c] += xa[c]*ya[c];
        }
        if (last) {
            float xe = (float)X[(size_t)rr * F_STRIDE_H + 1024];
            float ye = (float)Y[(size_t)rr * F_STRIDE_H + 1024];
            s5[0] += xe; s5[1] += ye; s5[2] += xe*xe; s5[3] += ye*ye; s5[4] += xe*ye;
        }
    }

    float4 ax, ay, bx, by; float a5x=0, a5y=0, b5x=0, b5y=0;
    ax = load4h(X + (size_t)(t_begin + 3) * F_STRIDE_H + fv);
    ay = load4h(Y + (size_t)(t_begin + 3) * F_STRIDE_H + fv);
    bx = load4h(X + (size_t)(t_begin - 3) * F_STRIDE_H + fv);
    by = load4h(Y + (size_t)(t_begin - 3) * F_STRIDE_H + fv);
    if (last) {
        a5x = (float)X[(size_t)(t_begin + 3) * F_STRIDE_H + 1024];
        a5y = (float)Y[(size_t)(t_begin + 3) * F_STRIDE_H + 1024];
        b5x = (float)X[(size_t)(t_begin - 3) * F_STRIDE_H + 1024];
        b5y = (float)Y[(size_t)(t_begin - 3) * F_STRIDE_H + 1024];
    }

    const int fo = 3 + (tid << 2);

    for (int t = t_begin; t < t_end_; ++t) {
        {
            float xa[4] = {ax.x, ax.y, ax.z, ax.w}, ya[4] = {ay.x, ay.y, ay.z, ay.w};
            #pragma unroll
            for (int c = 0; c < 4; ++c) {
                sx[c] += xa[c]; sy[c] += ya[c];
                sxx[c] += xa[c]*xa[c]; syy[c] += ya[c]*ya[c]; sxy[c] += xa[c]*ya[c];
                int p = 5 * tid + c;
                csx[p] = sx[c]; csy[p] = sy[c];
                csxx[p] = sxx[c]; csyy[p] = syy[c]; csxy[p] = sxy[c];
            }
            if (last) {
                s5[0] += a5x; s5[1] += a5y; s5[2] += a5x*a5x; s5[3] += a5y*a5y; s5[4] += a5x*a5y;
                csx[1280] = s5[0]; csy[1280] = s5[1];
                csxx[1280] = s5[2]; csyy[1280] = s5[3]; csxy[1280] = s5[4];
            }
        }
        __syncthreads();

        {
            float xa[4] = {bx.x, bx.y, bx.z, bx.w}, ya[4] = {by.x, by.y, by.z, by.w};
            #pragma unroll
            for (int c = 0; c < 4; ++c) {
                sx[c] -= xa[c]; sy[c] -= ya[c];
                sxx[c] -= xa[c]*xa[c]; syy[c] -= ya[c]*ya[c]; sxy[c] -= xa[c]*ya[c];
            }
            if (last) {
                s5[0] -= b5x; s5[1] -= b5y; s5[2] -= b5x*b5x; s5[3] -= b5y*b5y; s5[4] -= b5x*b5y;
            }
        }
        if (t + 1 < t_end_) {
            ax = load4h(X + (size_t)(t + 4) * F_STRIDE_H + fv);
            ay = load4h(Y + (size_t)(t + 4) * F_STRIDE_H + fv);
            bx = load4h(X + (size_t)(t - 2) * F_STRIDE_H + fv);
            by = load4h(Y + (size_t)(t - 2) * F_STRIDE_H + fv);
            if (last) {
                a5x = (float)X[(size_t)(t + 4) * F_STRIDE_H + 1024];
                a5y = (float)Y[(size_t)(t + 4) * F_STRIDE_H + 1024];
                b5x = (float)X[(size_t)(t - 2) * F_STRIDE_H + 1024];
                b5y = (float)Y[(size_t)(t - 2) * F_STRIDE_H + 1024];
            }
        }

        if (tid < 255) {
            float tx[10], ty[10], txx[10], tyy[10], txy[10];
            #pragma unroll
            for (int d = 0; d < 10; ++d) {
                int p = 5 * tid + d + (d >> 2);
                tx[d] = csx[p]; ty[d] = csy[p];
                txx[d] = csxx[p]; tyy[d] = csyy[p]; txy[d] = csxy[p];
            }
            float wx  = tx[0]+tx[1]+tx[2]+tx[3]+tx[4]+tx[5]+tx[6];
            float wy  = ty[0]+ty[1]+ty[2]+ty[3]+ty[4]+ty[5]+ty[6];
            float wxx = txx[0]+txx[1]+txx[2]+txx[3]+txx[4]+txx[5]+txx[6];
            float wyy = tyy[0]+tyy[1]+tyy[2]+tyy[3]+tyy[4]+tyy[5]+tyy[6];
            float wxy = txy[0]+txy[1]+txy[2]+txy[3]+txy[4]+txy[5]+txy[6];
            #pragma unroll
            for (int c = 0; c < 4; ++c) {
                if (fo + c <= 1021) {
                    float ux  = wx * inv49, uy  = wy * inv49;
                    float uxx = wxx * inv49, uyy = wyy * inv49, uxy = wxy * inv49;
                    float vx  = COV_NORM_ * (uxx - ux * ux);
                    float vy  = COV_NORM_ * (uyy - uy * uy);
                    float vxy = COV_NORM_ * (uxy - ux * uy);
                    float Sv = ((2.f * ux * uy + C1_) * (2.f * vxy + C2_)) /
                               ((ux * ux + uy * uy + C1_) * (vx + vy + C2_));
                    acc += (double)Sv;
                }
                if (c < 3) {
                    wx  += tx[c+7]  - tx[c];
                    wy  += ty[c+7]  - ty[c];
                    wxx += txx[c+7] - txx[c];
                    wyy += tyy[c+7] - tyy[c];
                    wxy += txy[c+7] - txy[c];
                }
            }
        }
        __syncthreads();
    }

    red[tid] = acc;
    __syncthreads();
    for (int off = 128; off > 0; off >>= 1) {
        if (tid < off) red[tid] += red[tid + off];
        __syncthreads();
    }
    if (tid == 0) {
        atomicAdd(&out[ch], (float)(red[0] / (395.0 * 1019.0)));
    }
}

extern "C" void kernel_launch(void* const* d_in, const int* in_sizes, int n_in,
                              void* d_out, int out_size, void* d_ws, size_t ws_size,
                              hipStream_t stream) {
    const float* x0 = (const float*)d_in[0];   // output
    const float* x1 = (const float*)d_in[1];   // target
    float* out = (float*)d_out;
    float* ws  = (float*)d_ws;

    const size_t table_bytes  = (size_t)SPEC_OFF * sizeof(float);
    const size_t per_ch_bytes = (size_t)2 * T_FRAMES * F_STRIDE_H * sizeof(half_t);
    int G = (int)((ws_size - table_bytes) / per_ch_bytes);
    if (G > N_CH) G = N_CH;
    if (G < 1)    G = 1;

    init_tables_kernel<<<dim3(16), dim3(256), 0, stream>>>(ws, out);

    for (int ch0 = 0; ch0 < N_CH; ch0 += G) {
        const int nch = (N_CH - ch0 < G) ? (N_CH - ch0) : G;

        if (nch == 64) {
            stft_mag_kernel<<<dim3(201 * 128), dim3(128), 0, stream>>>(x0, x1, ws, ch0, nch, 1);
        } else {
            stft_mag_kernel<<<dim3(402, nch), dim3(128), 0, stream>>>(x0, x1, ws, ch0, nch, 0);
        }

        dim3 g2(N_CHUNKS, nch);
        ssim_kernel<<<g2, 256, 0, stream>>>(ws, out, ch0, nch);
    }
}